// Round 5
// baseline (205.755 us; speedup 1.0000x reference)
//
#include <hip/hip_runtime.h>
#include <hip/hip_bf16.h>
#include <math.h>

// Re(C)[4096,8192] = Re( (softplus(W)*tau*cis(-2pi*j*k/4096)) @ FFT(softplus(H)) )
// 3-dispatch pipeline (round-0 chassis; make_A folded into the FFT dispatch):
//   K1 front     : blocks 0..255  : per-row 8192-pt FFT of softplus(H),
//                                   packed bf16 (Hr, -Hi), layout [k][c]
//                                   -> d_out[0..2M uints)  (coalesced store)
//                  blocks 256..319: make_A A2[4096][512] bf16 (Re,Im)
//                                   -> ws[0..4MB)  (no-LDS blocks co-resident
//                                   with FFT blocks -> overlapped, free)
//   K2 transpose : Hc[k][c] -> Hc_t[c][k] (1KB rows)      -> ws[4MB..12MB)
//   K3 gemm      : m97-pure bf16 MFMA GEMM (round-0 verbatim, measured-best),
//                  both operands via global_load_lds width16, K=512
//                  -> d_out (128MB f32 real part)
// All ws reads clamped, ws writes guarded, epilogue guarded: fault-free.

#define NROW 4096
#define RANKN 256
#define NCOL 8192
#define PI_F 3.14159265358979323846f

#define A2_U   (NROW * RANKN)            // 1M uints = 4MB  (A2 region, ws)
#define HT_OFF A2_U                      // Hc_t offset in ws (uints)
#define HT_U   (NCOL * RANKN)            // 2M uints = 8MB
#define WS_NEED (A2_U + HT_U)            // 3M uints = 12MB

typedef __attribute__((ext_vector_type(8))) short short8;
typedef __attribute__((ext_vector_type(4))) float floatx4;

__device__ static inline unsigned short f2bf(float f) {
    union { float f; unsigned int u; } v; v.f = f;
    unsigned int r = v.u + 0x7FFFu + ((v.u >> 16) & 1u);  // RNE
    return (unsigned short)(r >> 16);
}

__device__ static inline float softplus_f(float x) {
    return __logf(1.0f + __expf(x));   // inputs uniform[0,1): safe
}

// ===========================================================================
// K1: fused front end.
//   blocks 0..255  : 8192-pt FFT of softplus(H[row]), row = blockIdx.x;
//                    packed (Hr | (-Hi)<<16) -> Hc[row][c]  (coalesced)
//   blocks 256..319: make_A, 16 elems/thread (64*1024*16 = 1M elems exactly):
//                    ws[j*256+k] = (Re | Im<<16) of softplus(W)*tau*cis
// ===========================================================================
#define SW(i) ((i) ^ (((i) >> 5) & 31))

__device__ constexpr int brev_c(int x, int bits) {
    int r = 0;
    for (int i = 0; i < bits; ++i) r |= ((x >> i) & 1) << (bits - 1 - i);
    return r;
}

__device__ static inline void fft8_reg(float re[8], float im[8]) {
#pragma unroll
    for (int s = 1; s <= 3; ++s) {
        const int half = 1 << (s - 1);
#pragma unroll
        for (int b = 0; b < 4; ++b) {
            const int p  = b & (half - 1);
            const int g  = b >> (s - 1);
            const int i1 = (g << s) + p;
            const int i2 = i1 + half;
            const float ang = -PI_F * (float)p / (float)half;
            const float cw = __cosf(ang), sw = __sinf(ang);
            const float tr = cw * re[i2] - sw * im[i2];
            const float ti = cw * im[i2] + sw * re[i2];
            re[i2] = re[i1] - tr; im[i2] = im[i1] - ti;
            re[i1] += tr;         im[i1] += ti;
        }
    }
}

__device__ static inline void fft16_reg(float re[16], float im[16]) {
#pragma unroll
    for (int s = 1; s <= 4; ++s) {
        const int half = 1 << (s - 1);
#pragma unroll
        for (int b = 0; b < 8; ++b) {
            const int p  = b & (half - 1);
            const int g  = b >> (s - 1);
            const int i1 = (g << s) + p;
            const int i2 = i1 + half;
            const float ang = -PI_F * (float)p / (float)half;
            const float cw = __cosf(ang), sw = __sinf(ang);
            const float tr = cw * re[i2] - sw * im[i2];
            const float ti = cw * im[i2] + sw * re[i2];
            re[i2] = re[i1] - tr; im[i2] = im[i1] - ti;
            re[i1] += tr;         im[i1] += ti;
        }
    }
}

__global__ __launch_bounds__(1024) void front(const float* __restrict__ W,
                                              const float* __restrict__ H,
                                              const float* __restrict__ tau,
                                              unsigned int* __restrict__ ws,
                                              unsigned int* __restrict__ Hc,
                                              unsigned int ws_uints,
                                              unsigned int out_uints) {
    __shared__ float2 buf[8192];   // 64 KB (untouched by make_A blocks)
    const int t = threadIdx.x;     // 0..1023

    if (blockIdx.x >= RANKN) {
        // ---------------- make_A path (blocks 256..319) ----------------
        const int b2 = blockIdx.x - RANKN;   // 0..63
#pragma unroll
        for (int e = 0; e < 16; ++e) {
            const unsigned int idx = (unsigned int)(b2 * 16384 + e * 1024 + t);
            const int j = (int)(idx >> 8);
            const int k = (int)(idx & 255);
            const float st = softplus_f(W[idx]) * tau[idx];
            const int   m  = (j * k) & (NROW - 1);
            const float ang = (float)m * (-2.0f * PI_F / (float)NROW);
            const unsigned int v = (unsigned int)f2bf(st * __cosf(ang)) |
                                   ((unsigned int)f2bf(st * __sinf(ang)) << 16);
            if (idx < ws_uints) ws[idx] = v;
        }
        return;
    }

    // ---------------- FFT path (radix 8*8*8*16), round-0 verbatim ----------
    const int row = blockIdx.x;    // rank index
    const float* h = H + (size_t)row * NCOL;

    // load softplus(H row)
#pragma unroll
    for (int e = 0; e < 8; ++e) {
        const int n = t + 1024 * e;
        buf[SW(n)] = make_float2(softplus_f(h[n]), 0.0f);
    }
    __syncthreads();

    // L1: FFT-8 over a (stride 1024), twiddle W_8192^(t*a')
    {
        float re[8], im[8];
#pragma unroll
        for (int a = 0; a < 8; ++a) {
            const float2 v = buf[SW(1024 * a + t)];
            re[brev_c(a, 3)] = v.x; im[brev_c(a, 3)] = v.y;
        }
        fft8_reg(re, im);
#pragma unroll
        for (int ap = 0; ap < 8; ++ap) {
            const float ang = (-2.0f * PI_F / 8192.0f) * (float)(t * ap);
            const float cw = __cosf(ang), sw = __sinf(ang);
            buf[SW(ap * 1024 + t)] =
                make_float2(cw * re[ap] - sw * im[ap], cw * im[ap] + sw * re[ap]);
        }
    }
    __syncthreads();

    // L2: rows of 1024 (a1'): FFT-8 over b (stride 128), twiddle W_1024^(u*b')
    {
        const int a1 = t >> 7, u = t & 127;
        const int base = a1 * 1024;
        float re[8], im[8];
#pragma unroll
        for (int b = 0; b < 8; ++b) {
            const float2 v = buf[SW(base + 128 * b + u)];
            re[brev_c(b, 3)] = v.x; im[brev_c(b, 3)] = v.y;
        }
        fft8_reg(re, im);
#pragma unroll
        for (int bp = 0; bp < 8; ++bp) {
            const float ang = (-2.0f * PI_F / 1024.0f) * (float)(u * bp);
            const float cw = __cosf(ang), sw = __sinf(ang);
            buf[SW(base + bp * 128 + u)] =
                make_float2(cw * re[bp] - sw * im[bp], cw * im[bp] + sw * re[bp]);
        }
    }
    __syncthreads();

    // L3: sub-rows of 128 (a1',b'): FFT-8 over c (stride 16), twiddle W_128^(v*c')
    {
        const int a1 = t >> 7, b2 = (t >> 4) & 7, v0 = t & 15;
        const int base = a1 * 1024 + b2 * 128;
        float re[8], im[8];
#pragma unroll
        for (int c = 0; c < 8; ++c) {
            const float2 v = buf[SW(base + 16 * c + v0)];
            re[brev_c(c, 3)] = v.x; im[brev_c(c, 3)] = v.y;
        }
        fft8_reg(re, im);
#pragma unroll
        for (int cp = 0; cp < 8; ++cp) {
            const float ang = (-2.0f * PI_F / 128.0f) * (float)(v0 * cp);
            const float cw = __cosf(ang), sw = __sinf(ang);
            buf[SW(base + cp * 16 + v0)] =
                make_float2(cw * re[cp] - sw * im[cp], cw * im[cp] + sw * re[cp]);
        }
    }
    __syncthreads();

    // L4: 512 sub-blocks of 16: FFT-16 over v; scatter X[a1' + 8a2' + 64a3' + 512v']
    {
        float re[16], im[16];
        const int a1 = t >> 6, a2 = (t >> 3) & 7, a3 = t & 7;
        const int base = a1 * 1024 + a2 * 128 + a3 * 16;
        const int kb = a1 + 8 * a2 + 64 * a3;
        if (t < 512) {
#pragma unroll
            for (int v = 0; v < 16; ++v) {
                const float2 x = buf[SW(base + v)];
                re[brev_c(v, 4)] = x.x; im[brev_c(v, 4)] = x.y;
            }
        }
        __syncthreads();
        if (t < 512) {
            fft16_reg(re, im);
#pragma unroll
            for (int vp = 0; vp < 16; ++vp) {
                buf[SW(kb + 512 * vp)] = make_float2(re[vp], im[vp]);
            }
        }
        __syncthreads();
    }

    // store packed (Hr, -Hi), coalesced
    unsigned int* out = Hc + (size_t)row * NCOL;
#pragma unroll
    for (int e = 0; e < 8; ++e) {
        const int c = t + 1024 * e;
        const float2 v = buf[SW(c)];
        const unsigned int idx = (unsigned int)(row * NCOL + c);
        if (idx < out_uints)
            out[c] = (unsigned int)f2bf(v.x) |
                     (((unsigned int)f2bf(v.y) ^ 0x8000u) << 16);
    }
}

// ===========================================================================
// K2: transpose Hc[256][8192] (in d_out) -> Hc_t[8192][256] (ws + HT_OFF)
// ===========================================================================
__global__ __launch_bounds__(256) void transpose_H(const unsigned int* __restrict__ Hc,
                                                   unsigned int* __restrict__ ws,
                                                   unsigned int ws_uints) {
    __shared__ unsigned int tile[32][33];
    const int c0 = blockIdx.x * 32;   // column tile (n_col dim)
    const int k0 = blockIdx.y * 32;   // row tile (rank dim)
    const int tx = threadIdx.x & 31;
    const int ty = threadIdx.x >> 5;  // 0..7

#pragma unroll
    for (int e = 0; e < 4; ++e) {
        const int k = ty + e * 8;
        tile[k][tx] = Hc[(size_t)(k0 + k) * NCOL + c0 + tx];
    }
    __syncthreads();
#pragma unroll
    for (int e = 0; e < 4; ++e) {
        const int c = ty + e * 8;
        const unsigned int idx = HT_OFF + (unsigned int)(c0 + c) * RANKN + k0 + tx;
        if (idx < ws_uints) ws[idx] = tile[tx][c];
    }
}

// ===========================================================================
// K3: m97-pure GEMM (round-0 verbatim, measured-best 197.8us config).
// ReC[4096,8192] f32 = A2[4096,512]bf16 @ Hc_t[8192,512]^T
// 128x128 tile, BK=32, 256 thr (4 waves 2x2, 4x4 frags, 16x16x32 bf16 MFMA),
// both operands via global_load_lds width 16, unpadded [128][32]-short LDS.
// ===========================================================================
__device__ static inline void load16_to_lds(const unsigned int* g, void* l) {
    __builtin_amdgcn_global_load_lds(
        (const __attribute__((address_space(1))) unsigned int*)g,
        (__attribute__((address_space(3))) unsigned int*)l,
        16, 0, 0);
}

__global__ __launch_bounds__(256) void gemm_real(const unsigned int* __restrict__ ws,
                                                 float* __restrict__ C,
                                                 unsigned int out_lim,
                                                 unsigned int clamp_u) {
    __shared__ unsigned short As[128 * 32];  // [j][k'] 8 KB
    __shared__ unsigned short Bs[128 * 32];  // [c][k'] 8 KB

    const int tid  = threadIdx.x;
    const int wv   = tid >> 6;
    const int lane = tid & 63;
    const int quad = lane >> 4;
    const int l16  = lane & 15;

    const int j0 = blockIdx.y * 128;
    const int n0 = blockIdx.x * 128;
    const int wr = wv >> 1, wc = wv & 1;

    floatx4 zero = {0.0f, 0.0f, 0.0f, 0.0f};
    floatx4 acc[4][4];
    for (int i = 0; i < 4; ++i)
        for (int j = 0; j < 4; ++j) acc[i][j] = zero;

    int aoff[4], boff[4];
#pragma unroll
    for (int i = 0; i < 4; ++i) {
        aoff[i] = (wr * 64 + i * 16 + l16) * 32 + quad * 8;
        boff[i] = (wc * 64 + i * 16 + l16) * 32 + quad * 8;
    }

    // staging address components (row = q>>2 in [0,128), kc = q&3)
    const int qbase0 = wv * 128;            // p=0
    const int qbase1 = wv * 128 + 64;       // p=1

    for (int kt = 0; kt < 16; ++kt) {       // K = 512 shorts = 16 uints/row/iter
#pragma unroll
        for (int p = 0; p < 2; ++p) {
            const int qb  = p ? qbase1 : qbase0;
            const int q   = qb + lane;
            const int row = q >> 2;
            const int kc  = q & 3;
            // A: uint offset (j0+row)*256 + kt*16 + kc*4
            unsigned int ua = (unsigned int)((j0 + row) * RANKN + kt * 16 + kc * 4);
            ua = ua < clamp_u ? ua : clamp_u;
            // B: uint offset HT_OFF + (n0+row)*256 + kt*16 + kc*4
            unsigned int ub = (unsigned int)(HT_OFF + (n0 + row) * RANKN + kt * 16 + kc * 4);
            ub = ub < clamp_u ? ub : clamp_u;
            load16_to_lds(ws + ua, &As[qb * 8]);
            load16_to_lds(ws + ub, &Bs[qb * 8]);
        }
        __syncthreads();

        short8 af[4], bf[4];
#pragma unroll
        for (int i = 0; i < 4; ++i) af[i] = *(const short8*)&As[aoff[i]];
#pragma unroll
        for (int i = 0; i < 4; ++i) bf[i] = *(const short8*)&Bs[boff[i]];
#pragma unroll
        for (int mi = 0; mi < 4; ++mi)
#pragma unroll
            for (int ni = 0; ni < 4; ++ni)
                acc[mi][ni] = __builtin_amdgcn_mfma_f32_16x16x32_bf16(
                    af[mi], bf[ni], acc[mi][ni], 0, 0, 0);
        __syncthreads();
    }

    // epilogue: C/D layout col=lane&15, row=quad*4+reg (m89-verified), guarded
#pragma unroll
    for (int mi = 0; mi < 4; ++mi) {
#pragma unroll
        for (int ni = 0; ni < 4; ++ni) {
            const int row = j0 + wr * 64 + mi * 16 + quad * 4;
            const int col = n0 + wc * 64 + ni * 16 + l16;
#pragma unroll
            for (int r = 0; r < 4; ++r) {
                const unsigned int idx = (unsigned int)((row + r) * NCOL + col);
                if (idx < out_lim) C[idx] = acc[mi][ni][r];
            }
        }
    }
}

// ===========================================================================
extern "C" void kernel_launch(void* const* d_in, const int* in_sizes, int n_in,
                              void* d_out, int out_size, void* d_ws, size_t ws_size,
                              hipStream_t stream) {
    const float* W   = (const float*)d_in[0];   // [4096, 256]
    const float* H   = (const float*)d_in[1];   // [256, 8192]
    const float* tau = (const float*)d_in[2];   // [4096, 256]
    float* out = (float*)d_out;                 // [4096, 8192] f32 (real part)

    unsigned int* ws = (unsigned int*)d_ws;
    const unsigned int ws_uints = (unsigned int)(ws_size / 4);
    const unsigned int clamp_u  = ws_uints >= 4 ? ws_uints - 4 : 0;  // 16B-load clamp
    unsigned int* HcOut = (unsigned int*)d_out;  // Ht staged in d_out[0..2M uints)

    front<<<RANKN + 64, 1024, 0, stream>>>(W, H, tau, ws, HcOut, ws_uints,
                                           (unsigned int)out_size);
    transpose_H<<<dim3(NCOL / 32, RANKN / 32), 256, 0, stream>>>(HcOut, ws, ws_uints);
    gemm_real<<<dim3(NCOL / 128, NROW / 128), 256, 0, stream>>>(
        ws, out, (unsigned int)out_size, clamp_u);
}

// Round 6
// 197.930 us; speedup vs baseline: 1.0395x; 1.0395x over previous
//
#include <hip/hip_runtime.h>
#include <hip/hip_bf16.h>
#include <math.h>

// Re(C)[4096,8192] = Re( (softplus(W)*tau*cis(-2pi*j*k/4096)) @ FFT(softplus(H)) )
// Pipeline:
//   K1 make_A    : A2[4096][512] bf16 (Re,Im interleaved)          -> ws[0..4MB)
//   K2 fft_H     : per-row 8192-pt FFT of softplus(H), packed bf16
//                  (Hr, -Hi) per uint, layout [k][c]               -> d_out[0..8MB)
//   K3 transpose : Hc[k][c] -> Hc_t[c][k] (1KB rows)               -> ws[4MB..12MB)
//   K4 gemm      : m97-pure bf16 MFMA GEMM, both operands via
//                  global_load_lds width16, K=512                  -> d_out (128MB)
// All ws reads clamped, ws writes guarded, epilogue guarded: fault-free.
// NOTE: this is the measured-best configuration (197.8us R0, 198.2us R1
// reproduction). R1/R3/R4/R5 deviations (deeper GEMM schedule, dispatch
// fusion, scatter-store, counted pipeline) all measured equal or worse:
// the GEMM is C-write-bound (128MB f32 = ~20us at 6.3TB/s), the window is
// dominated by harness poison fills. Keep this structure.

#define NROW 4096
#define RANKN 256
#define NCOL 8192
#define PI_F 3.14159265358979323846f

#define A2_U   (NROW * RANKN)            // 1M uints = 4MB  (A2 region, ws)
#define HT_OFF A2_U                      // Hc_t offset in ws (uints)
#define HT_U   (NCOL * RANKN)            // 2M uints = 8MB
#define WS_NEED (A2_U + HT_U)            // 3M uints = 12MB

typedef __attribute__((ext_vector_type(8))) short short8;
typedef __attribute__((ext_vector_type(4))) float floatx4;

__device__ static inline unsigned short f2bf(float f) {
    union { float f; unsigned int u; } v; v.f = f;
    unsigned int r = v.u + 0x7FFFu + ((v.u >> 16) & 1u);  // RNE
    return (unsigned short)(r >> 16);
}

__device__ static inline float softplus_f(float x) {
    return __logf(1.0f + __expf(x));   // inputs uniform[0,1): safe
}

// ===========================================================================
// K1: A2[j][k'] packed uints: (Re | Im<<16) of softplus(W)*tau*cis(-2pi jk/4096)
// ===========================================================================
__global__ __launch_bounds__(256) void make_A(const float* __restrict__ W,
                                              const float* __restrict__ tau,
                                              unsigned int* __restrict__ ws,
                                              unsigned int ws_uints) {
    const int j = blockIdx.x;
    const int k = threadIdx.x;
    const unsigned int idx = j * RANKN + k;
    const float st = softplus_f(W[idx]) * tau[idx];
    const int   m  = (j * k) & (NROW - 1);
    const float ang = (float)m * (-2.0f * PI_F / (float)NROW);
    const unsigned int v = (unsigned int)f2bf(st * __cosf(ang)) |
                           ((unsigned int)f2bf(st * __sinf(ang)) << 16);
    if (idx < ws_uints) ws[idx] = v;
}

// ===========================================================================
// K2: per-row 8192-pt FFT, radix 8*8*8*16, 1024 threads, 64KB LDS.
// Output packed (Hr | (-Hi)<<16) uints, layout [k][c], into d_out[0..2M uints).
// ===========================================================================
#define SW(i) ((i) ^ (((i) >> 5) & 31))

__device__ constexpr int brev_c(int x, int bits) {
    int r = 0;
    for (int i = 0; i < bits; ++i) r |= ((x >> i) & 1) << (bits - 1 - i);
    return r;
}

__device__ static inline void fft8_reg(float re[8], float im[8]) {
#pragma unroll
    for (int s = 1; s <= 3; ++s) {
        const int half = 1 << (s - 1);
#pragma unroll
        for (int b = 0; b < 4; ++b) {
            const int p  = b & (half - 1);
            const int g  = b >> (s - 1);
            const int i1 = (g << s) + p;
            const int i2 = i1 + half;
            const float ang = -PI_F * (float)p / (float)half;
            const float cw = __cosf(ang), sw = __sinf(ang);
            const float tr = cw * re[i2] - sw * im[i2];
            const float ti = cw * im[i2] + sw * re[i2];
            re[i2] = re[i1] - tr; im[i2] = im[i1] - ti;
            re[i1] += tr;         im[i1] += ti;
        }
    }
}

__device__ static inline void fft16_reg(float re[16], float im[16]) {
#pragma unroll
    for (int s = 1; s <= 4; ++s) {
        const int half = 1 << (s - 1);
#pragma unroll
        for (int b = 0; b < 8; ++b) {
            const int p  = b & (half - 1);
            const int g  = b >> (s - 1);
            const int i1 = (g << s) + p;
            const int i2 = i1 + half;
            const float ang = -PI_F * (float)p / (float)half;
            const float cw = __cosf(ang), sw = __sinf(ang);
            const float tr = cw * re[i2] - sw * im[i2];
            const float ti = cw * im[i2] + sw * re[i2];
            re[i2] = re[i1] - tr; im[i2] = im[i1] - ti;
            re[i1] += tr;         im[i1] += ti;
        }
    }
}

__global__ __launch_bounds__(1024) void fft_H(const float* __restrict__ H,
                                              unsigned int* __restrict__ Hc,
                                              unsigned int out_uints) {
    __shared__ float2 buf[8192];   // 64 KB
    const int t = threadIdx.x;     // 0..1023
    const int row = blockIdx.x;    // rank index
    const float* h = H + (size_t)row * NCOL;

    // load softplus(H row)
#pragma unroll
    for (int e = 0; e < 8; ++e) {
        const int n = t + 1024 * e;
        buf[SW(n)] = make_float2(softplus_f(h[n]), 0.0f);
    }
    __syncthreads();

    // L1: FFT-8 over a (stride 1024), twiddle W_8192^(t*a')
    {
        float re[8], im[8];
#pragma unroll
        for (int a = 0; a < 8; ++a) {
            const float2 v = buf[SW(1024 * a + t)];
            re[brev_c(a, 3)] = v.x; im[brev_c(a, 3)] = v.y;
        }
        fft8_reg(re, im);
#pragma unroll
        for (int ap = 0; ap < 8; ++ap) {
            const float ang = (-2.0f * PI_F / 8192.0f) * (float)(t * ap);
            const float cw = __cosf(ang), sw = __sinf(ang);
            buf[SW(ap * 1024 + t)] =
                make_float2(cw * re[ap] - sw * im[ap], cw * im[ap] + sw * re[ap]);
        }
    }
    __syncthreads();

    // L2: rows of 1024 (a1'): FFT-8 over b (stride 128), twiddle W_1024^(u*b')
    {
        const int a1 = t >> 7, u = t & 127;
        const int base = a1 * 1024;
        float re[8], im[8];
#pragma unroll
        for (int b = 0; b < 8; ++b) {
            const float2 v = buf[SW(base + 128 * b + u)];
            re[brev_c(b, 3)] = v.x; im[brev_c(b, 3)] = v.y;
        }
        fft8_reg(re, im);
#pragma unroll
        for (int bp = 0; bp < 8; ++bp) {
            const float ang = (-2.0f * PI_F / 1024.0f) * (float)(u * bp);
            const float cw = __cosf(ang), sw = __sinf(ang);
            buf[SW(base + bp * 128 + u)] =
                make_float2(cw * re[bp] - sw * im[bp], cw * im[bp] + sw * re[bp]);
        }
    }
    __syncthreads();

    // L3: sub-rows of 128 (a1',b'): FFT-8 over c (stride 16), twiddle W_128^(v*c')
    {
        const int a1 = t >> 7, b2 = (t >> 4) & 7, v0 = t & 15;
        const int base = a1 * 1024 + b2 * 128;
        float re[8], im[8];
#pragma unroll
        for (int c = 0; c < 8; ++c) {
            const float2 v = buf[SW(base + 16 * c + v0)];
            re[brev_c(c, 3)] = v.x; im[brev_c(c, 3)] = v.y;
        }
        fft8_reg(re, im);
#pragma unroll
        for (int cp = 0; cp < 8; ++cp) {
            const float ang = (-2.0f * PI_F / 128.0f) * (float)(v0 * cp);
            const float cw = __cosf(ang), sw = __sinf(ang);
            buf[SW(base + cp * 16 + v0)] =
                make_float2(cw * re[cp] - sw * im[cp], cw * im[cp] + sw * re[cp]);
        }
    }
    __syncthreads();

    // L4: 512 sub-blocks of 16: FFT-16 over v; scatter X[a1' + 8a2' + 64a3' + 512v']
    {
        float re[16], im[16];
        const int a1 = t >> 6, a2 = (t >> 3) & 7, a3 = t & 7;
        const int base = a1 * 1024 + a2 * 128 + a3 * 16;
        const int kb = a1 + 8 * a2 + 64 * a3;
        if (t < 512) {
#pragma unroll
            for (int v = 0; v < 16; ++v) {
                const float2 x = buf[SW(base + v)];
                re[brev_c(v, 4)] = x.x; im[brev_c(v, 4)] = x.y;
            }
        }
        __syncthreads();
        if (t < 512) {
            fft16_reg(re, im);
#pragma unroll
            for (int vp = 0; vp < 16; ++vp) {
                buf[SW(kb + 512 * vp)] = make_float2(re[vp], im[vp]);
            }
        }
        __syncthreads();
    }

    // store packed (Hr, -Hi), coalesced
    unsigned int* out = Hc + (size_t)row * NCOL;
#pragma unroll
    for (int e = 0; e < 8; ++e) {
        const int c = t + 1024 * e;
        const float2 v = buf[SW(c)];
        const unsigned int idx = (unsigned int)(row * NCOL + c);
        if (idx < out_uints)
            out[c] = (unsigned int)f2bf(v.x) |
                     (((unsigned int)f2bf(v.y) ^ 0x8000u) << 16);
    }
}

// ===========================================================================
// K3: transpose Hc[256][8192] (in d_out) -> Hc_t[8192][256] (ws + HT_OFF)
// ===========================================================================
__global__ __launch_bounds__(256) void transpose_H(const unsigned int* __restrict__ Hc,
                                                   unsigned int* __restrict__ ws,
                                                   unsigned int ws_uints) {
    __shared__ unsigned int tile[32][33];
    const int c0 = blockIdx.x * 32;   // column tile (n_col dim)
    const int k0 = blockIdx.y * 32;   // row tile (rank dim)
    const int tx = threadIdx.x & 31;
    const int ty = threadIdx.x >> 5;  // 0..7

#pragma unroll
    for (int e = 0; e < 4; ++e) {
        const int k = ty + e * 8;
        tile[k][tx] = Hc[(size_t)(k0 + k) * NCOL + c0 + tx];
    }
    __syncthreads();
#pragma unroll
    for (int e = 0; e < 4; ++e) {
        const int c = ty + e * 8;
        const unsigned int idx = HT_OFF + (unsigned int)(c0 + c) * RANKN + k0 + tx;
        if (idx < ws_uints) ws[idx] = tile[tx][c];
    }
}

// ===========================================================================
// K4: m97-pure GEMM. ReC[4096,8192] f32 = A2[4096,512]bf16 @ Hc_t[8192,512]^T
// 128x128 tile, BK=32, 256 thr (4 waves 2x2, 4x4 frags, 16x16x32 bf16 MFMA),
// both operands via global_load_lds width 16, unpadded [128][32]-short LDS.
// ===========================================================================
__device__ static inline void load16_to_lds(const unsigned int* g, void* l) {
    __builtin_amdgcn_global_load_lds(
        (const __attribute__((address_space(1))) unsigned int*)g,
        (__attribute__((address_space(3))) unsigned int*)l,
        16, 0, 0);
}

__global__ __launch_bounds__(256) void gemm_real(const unsigned int* __restrict__ ws,
                                                 float* __restrict__ C,
                                                 unsigned int out_lim,
                                                 unsigned int clamp_u) {
    __shared__ unsigned short As[128 * 32];  // [j][k'] 8 KB
    __shared__ unsigned short Bs[128 * 32];  // [c][k'] 8 KB

    const int tid  = threadIdx.x;
    const int wv   = tid >> 6;
    const int lane = tid & 63;
    const int quad = lane >> 4;
    const int l16  = lane & 15;

    const int j0 = blockIdx.y * 128;
    const int n0 = blockIdx.x * 128;
    const int wr = wv >> 1, wc = wv & 1;

    floatx4 zero = {0.0f, 0.0f, 0.0f, 0.0f};
    floatx4 acc[4][4];
    for (int i = 0; i < 4; ++i)
        for (int j = 0; j < 4; ++j) acc[i][j] = zero;

    int aoff[4], boff[4];
#pragma unroll
    for (int i = 0; i < 4; ++i) {
        aoff[i] = (wr * 64 + i * 16 + l16) * 32 + quad * 8;
        boff[i] = (wc * 64 + i * 16 + l16) * 32 + quad * 8;
    }

    // staging address components (row = q>>2 in [0,128), kc = q&3)
    const int qbase0 = wv * 128;            // p=0
    const int qbase1 = wv * 128 + 64;       // p=1

    for (int kt = 0; kt < 16; ++kt) {       // K = 512 shorts = 16 uints/row/iter
#pragma unroll
        for (int p = 0; p < 2; ++p) {
            const int qb  = p ? qbase1 : qbase0;
            const int q   = qb + lane;
            const int row = q >> 2;
            const int kc  = q & 3;
            // A: uint offset (j0+row)*256 + kt*16 + kc*4
            unsigned int ua = (unsigned int)((j0 + row) * RANKN + kt * 16 + kc * 4);
            ua = ua < clamp_u ? ua : clamp_u;
            // B: uint offset HT_OFF + (n0+row)*256 + kt*16 + kc*4
            unsigned int ub = (unsigned int)(HT_OFF + (n0 + row) * RANKN + kt * 16 + kc * 4);
            ub = ub < clamp_u ? ub : clamp_u;
            load16_to_lds(ws + ua, &As[qb * 8]);
            load16_to_lds(ws + ub, &Bs[qb * 8]);
        }
        __syncthreads();

        short8 af[4], bf[4];
#pragma unroll
        for (int i = 0; i < 4; ++i) af[i] = *(const short8*)&As[aoff[i]];
#pragma unroll
        for (int i = 0; i < 4; ++i) bf[i] = *(const short8*)&Bs[boff[i]];
#pragma unroll
        for (int mi = 0; mi < 4; ++mi)
#pragma unroll
            for (int ni = 0; ni < 4; ++ni)
                acc[mi][ni] = __builtin_amdgcn_mfma_f32_16x16x32_bf16(
                    af[mi], bf[ni], acc[mi][ni], 0, 0, 0);
        __syncthreads();
    }

    // epilogue: C/D layout col=lane&15, row=quad*4+reg (m89-verified), guarded
#pragma unroll
    for (int mi = 0; mi < 4; ++mi) {
#pragma unroll
        for (int ni = 0; ni < 4; ++ni) {
            const int row = j0 + wr * 64 + mi * 16 + quad * 4;
            const int col = n0 + wc * 64 + ni * 16 + l16;
#pragma unroll
            for (int r = 0; r < 4; ++r) {
                const unsigned int idx = (unsigned int)((row + r) * NCOL + col);
                if (idx < out_lim) C[idx] = acc[mi][ni][r];
            }
        }
    }
}

// ===========================================================================
extern "C" void kernel_launch(void* const* d_in, const int* in_sizes, int n_in,
                              void* d_out, int out_size, void* d_ws, size_t ws_size,
                              hipStream_t stream) {
    const float* W   = (const float*)d_in[0];   // [4096, 256]
    const float* H   = (const float*)d_in[1];   // [256, 8192]
    const float* tau = (const float*)d_in[2];   // [4096, 256]
    float* out = (float*)d_out;                 // [4096, 8192] f32 (real part)

    unsigned int* ws = (unsigned int*)d_ws;
    const unsigned int ws_uints = (unsigned int)(ws_size / 4);
    const unsigned int clamp_u  = ws_uints >= 4 ? ws_uints - 4 : 0;  // 16B-load clamp
    unsigned int* HcOut = (unsigned int*)d_out;  // Ht staged in d_out[0..2M uints)

    make_A<<<NROW, RANKN, 0, stream>>>(W, tau, ws, ws_uints);
    fft_H<<<RANKN, 1024, 0, stream>>>(H, HcOut, (unsigned int)out_size);
    transpose_H<<<dim3(NCOL / 32, RANKN / 32), 256, 0, stream>>>(HcOut, ws, ws_uints);
    gemm_real<<<dim3(NCOL / 128, NROW / 128), 256, 0, stream>>>(
        ws, out, (unsigned int)out_size, clamp_u);
}